// Round 3
// baseline (101.503 us; speedup 1.0000x reference)
//
#include <hip/hip_runtime.h>
#include <math.h>

// ContrastiveLoss: B=16384, D=64, fp32 in, scalar fp32 out.
// loss_i = logsumexp_j(sim[i,j]) - sim[i,i];  out = mean_i(loss_i)
// sim = normalize_rows(A) @ normalize_rows(B)^T / 0.07
//
// Round 3: same bf16-MFMA + fused-exp2 engine as round 2, but the j-loop is
// fully unrolled with an explicit 2-deep B-fragment prefetch pipeline so the
// L2 load latency (~200-300 cyc) hides under the previous iterations' MFMA+exp
// work instead of stalling every iteration (round-2 counters: VALU 34%, MFMA
// 16%, ~50% of cycles unaccounted = load-use stalls).

#define NROWS 16384
#define DIM 64
#define INV_T 14.285714285714286f           // 1/0.07
#define LOG2E 1.44269504088896340736f
#define LN2   0.69314718055994530942f
#define SCALE (INV_T * LOG2E)               // fold 1/T and log2(e) into A

#define JC    32                            // j-chunks (parallelism)
#define JPC   (NROWS / JC)                  // 512 j per chunk
#define JTILES (JPC / 16)                   // 32 16-row B tiles per chunk
#define WROWS 64                            // rows per wave (4 MFMA tiles)
#define BROWS 256                           // rows per block (4 waves)

typedef __attribute__((ext_vector_type(8))) short bf16x8;  // 8 bf16 = 4 VGPRs
typedef __attribute__((ext_vector_type(4))) float f32x4;

static __device__ __forceinline__ unsigned short f2bf(float f) {
    unsigned int u = __float_as_uint(f);
    unsigned int r = (u + 0x7fffu + ((u >> 16) & 1u)) >> 16;   // RNE
    return (unsigned short)r;
}

// ------- kernel 1: normalize rows of BOTH inputs -> bf16 (A pre-scaled) ----
__global__ __launch_bounds__(256) void nrm_bf16_kernel(
        const float* __restrict__ A, const float* __restrict__ B,
        unsigned short* __restrict__ Ab, unsigned short* __restrict__ Bb) {
    int wid  = (blockIdx.x * 256 + threadIdx.x) >> 6;   // 0..2*NROWS-1
    int lane = threadIdx.x & 63;
    const float* in;
    unsigned short* out;
    float scale;
    int row;
    if (wid < NROWS) { in = A; out = Ab; scale = SCALE; row = wid; }
    else             { in = B; out = Bb; scale = 1.0f;  row = wid - NROWS; }
    float x  = in[row * DIM + lane];
    float ss = x * x;
    #pragma unroll
    for (int m = 32; m >= 1; m >>= 1) ss += __shfl_xor(ss, m, 64);
    out[row * DIM + lane] = f2bf(x * rsqrtf(ss) * scale);
}

// -------- kernel 2: MFMA sim tiles + exp2 row-sum partials -----------------
__global__ __launch_bounds__(256) void simexp_kernel(
        const unsigned short* __restrict__ Ab,
        const unsigned short* __restrict__ Bb,
        float* __restrict__ partials) {
    const int lane = threadIdx.x & 63;
    const int wid  = threadIdx.x >> 6;                  // wave in block
    const int jc   = blockIdx.x & (JC - 1);
    const int rb   = blockIdx.x / JC;
    const int i0   = rb * BROWS + wid * WROWS;          // wave's first row
    const int lr   = lane & 15;                         // fragment row/col
    const int lk   = lane >> 4;                         // k-group (×8)

    bf16x8 a[4][2];
    #pragma unroll
    for (int t = 0; t < 4; ++t) {
        const unsigned short* ap = Ab + (size_t)(i0 + t * 16 + lr) * DIM + lk * 8;
        a[t][0] = *(const bf16x8*)(ap);
        a[t][1] = *(const bf16x8*)(ap + 32);
    }

    float es[4][4];
    #pragma unroll
    for (int t = 0; t < 4; ++t)
        #pragma unroll
        for (int r = 0; r < 4; ++r) es[t][r] = 0.0f;

    const f32x4 zero = {0.f, 0.f, 0.f, 0.f};
    const unsigned short* bp = Bb + (size_t)(jc * JPC + lr) * DIM + lk * 8;
    // B tile jt lives at bp + jt*16*DIM (frag0) and +32 (frag1).

    // 2-deep prefetch pipeline, fully unrolled (static indices only).
    bf16x8 c0 = *(const bf16x8*)(bp);
    bf16x8 c1 = *(const bf16x8*)(bp + 32);
    bf16x8 n0 = *(const bf16x8*)(bp + 16 * DIM);
    bf16x8 n1 = *(const bf16x8*)(bp + 16 * DIM + 32);

    #pragma unroll
    for (int jt = 0; jt < JTILES; ++jt) {
        bf16x8 m0, m1;
        if (jt + 2 < JTILES) {
            m0 = *(const bf16x8*)(bp + (jt + 2) * 16 * DIM);
            m1 = *(const bf16x8*)(bp + (jt + 2) * 16 * DIM + 32);
        }
        #pragma unroll
        for (int t = 0; t < 4; ++t) {
            f32x4 acc = __builtin_amdgcn_mfma_f32_16x16x32_bf16(a[t][0], c0, zero, 0, 0, 0);
            acc = __builtin_amdgcn_mfma_f32_16x16x32_bf16(a[t][1], c1, acc, 0, 0, 0);
            #pragma unroll
            for (int r = 0; r < 4; ++r)
                es[t][r] += __builtin_amdgcn_exp2f(acc[r]);
        }
        c0 = n0; c1 = n1; n0 = m0; n1 = m1;             // unrolled: free renames
    }

    // es[t][r]: partial over this lane's 16-col slice of row i0+t*16+lk*4+r.
    #pragma unroll
    for (int t = 0; t < 4; ++t)
        #pragma unroll
        for (int r = 0; r < 4; ++r) {
            float v = es[t][r];
            v += __shfl_xor(v, 1, 64);
            v += __shfl_xor(v, 2, 64);
            v += __shfl_xor(v, 4, 64);
            v += __shfl_xor(v, 8, 64);
            es[t][r] = v;
        }

    if (lr == 0) {                                      // lanes 0,16,32,48
        float* pout = partials + (size_t)jc * NROWS + i0;
        #pragma unroll
        for (int t = 0; t < 4; ++t) {
            f32x4 v = {es[t][0], es[t][1], es[t][2], es[t][3]};
            *(f32x4*)(pout + t * 16 + lk * 4) = v;      // rows lk*4..lk*4+3
        }
    }
}

// -------- kernel 3: per-row loss; diag from raw fp32 inputs ----------------
__global__ __launch_bounds__(256) void rowloss_kernel(
        const float* __restrict__ A, const float* __restrict__ B,
        const float* __restrict__ partials, float* __restrict__ rowloss) {
    int row  = (blockIdx.x * 256 + threadIdx.x) >> 6;
    int lane = threadIdx.x & 63;
    float a = A[row * DIM + lane];
    float b = B[row * DIM + lane];
    float saa = a * a, sbb = b * b, sab = a * b;
    #pragma unroll
    for (int m = 32; m >= 1; m >>= 1) {
        saa += __shfl_xor(saa, m, 64);
        sbb += __shfl_xor(sbb, m, 64);
        sab += __shfl_xor(sab, m, 64);
    }
    if (lane == 0) {
        float S = 0.f;
        #pragma unroll
        for (int c = 0; c < JC; ++c) S += partials[(size_t)c * NROWS + row];
        float diag = sab * rsqrtf(saa * sbb);           // exact fp32 cos-sim
        rowloss[row] = LN2 * __builtin_amdgcn_logf(S) - diag * INV_T;
    }
}

// -------- kernel 4: deterministic mean over 16384 row losses ---------------
__global__ __launch_bounds__(1024) void mean_kernel(
        const float* __restrict__ rowloss, float* __restrict__ out) {
    float s = 0.f;
    for (int idx = threadIdx.x; idx < NROWS; idx += 1024) s += rowloss[idx];
    __shared__ float red[16];
    #pragma unroll
    for (int m = 32; m >= 1; m >>= 1) s += __shfl_xor(s, m, 64);
    if ((threadIdx.x & 63) == 0) red[threadIdx.x >> 6] = s;
    __syncthreads();
    if (threadIdx.x < 16) {
        float t = red[threadIdx.x];
        #pragma unroll
        for (int m = 8; m >= 1; m >>= 1) t += __shfl_xor(t, m, 16);
        if (threadIdx.x == 0) out[0] = t * (1.0f / NROWS);
    }
}

extern "C" void kernel_launch(void* const* d_in, const int* in_sizes, int n_in,
                              void* d_out, int out_size, void* d_ws, size_t ws_size,
                              hipStream_t stream) {
    const float* A  = (const float*)d_in[0];
    const float* Bm = (const float*)d_in[1];
    float* out = (float*)d_out;

    unsigned short* Ab = (unsigned short*)d_ws;                 // 2 MiB
    unsigned short* Bb = Ab + (size_t)NROWS * DIM;              // 2 MiB
    float* partials    = (float*)(Bb + (size_t)NROWS * DIM);    // 2 MiB
    float* rowloss     = partials + (size_t)JC * NROWS;         // 64 KiB

    nrm_bf16_kernel<<<2 * NROWS / 4, 256, 0, stream>>>(A, Bm, Ab, Bb);
    simexp_kernel<<<(NROWS / BROWS) * JC, 256, 0, stream>>>(Ab, Bb, partials);
    rowloss_kernel<<<NROWS / 4, 256, 0, stream>>>(A, Bm, partials, rowloss);
    mean_kernel<<<1, 1024, 0, stream>>>(rowloss, out);
}

// Round 4
// 91.558 us; speedup vs baseline: 1.1086x; 1.1086x over previous
//
#include <hip/hip_runtime.h>
#include <math.h>

// ContrastiveLoss: B=16384, D=64, fp32 in, scalar fp32 out.
// loss_i = logsumexp_j(sim[i,j]) - sim[i,i];  out = mean_i(loss_i)
// sim = normalize_rows(A) @ normalize_rows(B)^T / 0.07
//
// Round 4: round-2 engine with a software pipeline achieved by ORDERING, not
// unrolling (round 3's full unroll hit 140 VGPR -> 10% occupancy -> slower).
// Per iteration: issue B loads for tile jt, then exp/add the PREVIOUS tile's
// accumulators (pure register trans+VALU work, ~160cyc), then MFMA tile jt.
// This puts real work between the global_load issue and its vmcnt wait, and
// between each MFMA and the exp that consumes it, with zero extra registers.

#define NROWS 16384
#define DIM 64
#define INV_T 14.285714285714286f           // 1/0.07
#define LOG2E 1.44269504088896340736f
#define LN2   0.69314718055994530942f
#define SCALE (INV_T * LOG2E)               // fold 1/T and log2(e) into A

#define JC    32                            // j-chunks (parallelism)
#define JPC   (NROWS / JC)                  // 512 j per chunk
#define JTILES (JPC / 16)                   // 32 16-row B tiles per chunk
#define WROWS 64                            // rows per wave (4 MFMA tiles)
#define BROWS 256                           // rows per block (4 waves)

typedef __attribute__((ext_vector_type(8))) short bf16x8;  // 8 bf16 = 4 VGPRs
typedef __attribute__((ext_vector_type(4))) float f32x4;

static __device__ __forceinline__ unsigned short f2bf(float f) {
    unsigned int u = __float_as_uint(f);
    unsigned int r = (u + 0x7fffu + ((u >> 16) & 1u)) >> 16;   // RNE
    return (unsigned short)r;
}

// ------- kernel 1: normalize rows of BOTH inputs -> bf16 (A pre-scaled) ----
__global__ __launch_bounds__(256) void nrm_bf16_kernel(
        const float* __restrict__ A, const float* __restrict__ B,
        unsigned short* __restrict__ Ab, unsigned short* __restrict__ Bb) {
    int wid  = (blockIdx.x * 256 + threadIdx.x) >> 6;   // 0..2*NROWS-1
    int lane = threadIdx.x & 63;
    const float* in;
    unsigned short* out;
    float scale;
    int row;
    if (wid < NROWS) { in = A; out = Ab; scale = SCALE; row = wid; }
    else             { in = B; out = Bb; scale = 1.0f;  row = wid - NROWS; }
    float x  = in[row * DIM + lane];
    float ss = x * x;
    #pragma unroll
    for (int m = 32; m >= 1; m >>= 1) ss += __shfl_xor(ss, m, 64);
    out[row * DIM + lane] = f2bf(x * rsqrtf(ss) * scale);
}

// -------- kernel 2: MFMA sim tiles + exp2 row-sum partials -----------------
__global__ __launch_bounds__(256) void simexp_kernel(
        const unsigned short* __restrict__ Ab,
        const unsigned short* __restrict__ Bb,
        float* __restrict__ partials) {
    const int lane = threadIdx.x & 63;
    const int wid  = threadIdx.x >> 6;                  // wave in block
    const int jc   = blockIdx.x & (JC - 1);
    const int rb   = blockIdx.x / JC;
    const int i0   = rb * BROWS + wid * WROWS;          // wave's first row
    const int lr   = lane & 15;                         // fragment row/col
    const int lk   = lane >> 4;                         // k-group (×8)

    bf16x8 a[4][2];
    #pragma unroll
    for (int t = 0; t < 4; ++t) {
        const unsigned short* ap = Ab + (size_t)(i0 + t * 16 + lr) * DIM + lk * 8;
        a[t][0] = *(const bf16x8*)(ap);
        a[t][1] = *(const bf16x8*)(ap + 32);
    }

    float es[4][4];
    #pragma unroll
    for (int t = 0; t < 4; ++t)
        #pragma unroll
        for (int r = 0; r < 4; ++r) es[t][r] = 0.0f;

    const f32x4 zero = {0.f, 0.f, 0.f, 0.f};
    const unsigned short* bp = Bb + (size_t)(jc * JPC + lr) * DIM + lk * 8;

    // ---- prologue: tile 0 -> accp ----
    bf16x8 c0 = *(const bf16x8*)(bp);
    bf16x8 c1 = *(const bf16x8*)(bp + 32);
    bp += 16 * DIM;
    f32x4 accp[4];
    #pragma unroll
    for (int t = 0; t < 4; ++t) {
        accp[t] = __builtin_amdgcn_mfma_f32_16x16x32_bf16(a[t][0], c0, zero, 0, 0, 0);
        accp[t] = __builtin_amdgcn_mfma_f32_16x16x32_bf16(a[t][1], c1, accp[t], 0, 0, 0);
    }

    // ---- steady state: loads(jt) | exp(jt-1) | MFMA(jt) ----
    for (int jt = 1; jt < JTILES; ++jt) {
        bf16x8 n0 = *(const bf16x8*)(bp);
        bf16x8 n1 = *(const bf16x8*)(bp + 32);
        bp += 16 * DIM;
        #pragma unroll
        for (int t = 0; t < 4; ++t)
            #pragma unroll
            for (int r = 0; r < 4; ++r)
                es[t][r] += __builtin_amdgcn_exp2f(accp[t][r]);
        #pragma unroll
        for (int t = 0; t < 4; ++t) {
            accp[t] = __builtin_amdgcn_mfma_f32_16x16x32_bf16(a[t][0], n0, zero, 0, 0, 0);
            accp[t] = __builtin_amdgcn_mfma_f32_16x16x32_bf16(a[t][1], n1, accp[t], 0, 0, 0);
        }
    }
    // ---- epilogue: exp of last tile ----
    #pragma unroll
    for (int t = 0; t < 4; ++t)
        #pragma unroll
        for (int r = 0; r < 4; ++r)
            es[t][r] += __builtin_amdgcn_exp2f(accp[t][r]);

    // es[t][r]: partial over this lane's 16-col slice of row i0+t*16+lk*4+r.
    #pragma unroll
    for (int t = 0; t < 4; ++t)
        #pragma unroll
        for (int r = 0; r < 4; ++r) {
            float v = es[t][r];
            v += __shfl_xor(v, 1, 64);
            v += __shfl_xor(v, 2, 64);
            v += __shfl_xor(v, 4, 64);
            v += __shfl_xor(v, 8, 64);
            es[t][r] = v;
        }

    if (lr == 0) {                                      // lanes 0,16,32,48
        float* pout = partials + (size_t)jc * NROWS + i0;
        #pragma unroll
        for (int t = 0; t < 4; ++t) {
            f32x4 v = {es[t][0], es[t][1], es[t][2], es[t][3]};
            *(f32x4*)(pout + t * 16 + lk * 4) = v;      // rows lk*4..lk*4+3
        }
    }
}

// -------- kernel 3: per-row loss; diag from raw fp32 inputs ----------------
__global__ __launch_bounds__(256) void rowloss_kernel(
        const float* __restrict__ A, const float* __restrict__ B,
        const float* __restrict__ partials, float* __restrict__ rowloss) {
    int row  = (blockIdx.x * 256 + threadIdx.x) >> 6;
    int lane = threadIdx.x & 63;
    float a = A[row * DIM + lane];
    float b = B[row * DIM + lane];
    float saa = a * a, sbb = b * b, sab = a * b;
    #pragma unroll
    for (int m = 32; m >= 1; m >>= 1) {
        saa += __shfl_xor(saa, m, 64);
        sbb += __shfl_xor(sbb, m, 64);
        sab += __shfl_xor(sab, m, 64);
    }
    if (lane == 0) {
        float S = 0.f;
        #pragma unroll
        for (int c = 0; c < JC; ++c) S += partials[(size_t)c * NROWS + row];
        float diag = sab * rsqrtf(saa * sbb);           // exact fp32 cos-sim
        rowloss[row] = LN2 * __builtin_amdgcn_logf(S) - diag * INV_T;
    }
}

// -------- kernel 4: deterministic mean over 16384 row losses ---------------
__global__ __launch_bounds__(1024) void mean_kernel(
        const float* __restrict__ rowloss, float* __restrict__ out) {
    float s = 0.f;
    for (int idx = threadIdx.x; idx < NROWS; idx += 1024) s += rowloss[idx];
    __shared__ float red[16];
    #pragma unroll
    for (int m = 32; m >= 1; m >>= 1) s += __shfl_xor(s, m, 64);
    if ((threadIdx.x & 63) == 0) red[threadIdx.x >> 6] = s;
    __syncthreads();
    if (threadIdx.x < 16) {
        float t = red[threadIdx.x];
        #pragma unroll
        for (int m = 8; m >= 1; m >>= 1) t += __shfl_xor(t, m, 16);
        if (threadIdx.x == 0) out[0] = t * (1.0f / NROWS);
    }
}

extern "C" void kernel_launch(void* const* d_in, const int* in_sizes, int n_in,
                              void* d_out, int out_size, void* d_ws, size_t ws_size,
                              hipStream_t stream) {
    const float* A  = (const float*)d_in[0];
    const float* Bm = (const float*)d_in[1];
    float* out = (float*)d_out;

    unsigned short* Ab = (unsigned short*)d_ws;                 // 2 MiB
    unsigned short* Bb = Ab + (size_t)NROWS * DIM;              // 2 MiB
    float* partials    = (float*)(Bb + (size_t)NROWS * DIM);    // 2 MiB
    float* rowloss     = partials + (size_t)JC * NROWS;         // 64 KiB

    nrm_bf16_kernel<<<2 * NROWS / 4, 256, 0, stream>>>(A, Bm, Ab, Bb);
    simexp_kernel<<<(NROWS / BROWS) * JC, 256, 0, stream>>>(Ab, Bb, partials);
    rowloss_kernel<<<NROWS / 4, 256, 0, stream>>>(A, Bm, partials, rowloss);
    mean_kernel<<<1, 1024, 0, stream>>>(rowloss, out);
}

// Round 5
// 73.254 us; speedup vs baseline: 1.3856x; 1.2499x over previous
//
#include <hip/hip_runtime.h>
#include <math.h>

// ContrastiveLoss: B=16384, D=64, fp32 in, scalar fp32 out.
// loss_i = logsumexp_j(sim[i,j]) - sim[i,i];  out = mean_i(loss_i)
// sim = normalize_rows(A) @ normalize_rows(B)^T / 0.07
//
// Round 5: LDS-staged B. Each block stages its ENTIRE 32KB B-chunk (256 rows)
// into LDS once via global_load_lds(16B), then runs a pure-LDS main loop with
// no vmcnt stalls (round-2/4 counters: ~50% of cycles all-wave vmcnt stall,
// plus 4x redundant B loads across the block's 4 waves). LDS uses the G4
// XOR swizzle (byte ^= (row&7)<<4) applied per rule #21: linear LDS dest +
// permuted per-lane GLOBAL source + XOR'd ds_read base (both loop-invariant).
// Trans-pipe floor for 268M v_exp_f32 at 1/4 rate is ~27us; target 35-45.

#define NROWS 16384
#define DIM 64
#define INV_T 14.285714285714286f           // 1/0.07
#define LOG2E 1.44269504088896340736f
#define LN2   0.69314718055994530942f
#define SCALE (INV_T * LOG2E)               // fold 1/T and log2(e) into A

#define JC     64                           // j-chunks; == wavefront size
#define JPC    (NROWS / JC)                 // 256 j per chunk
#define NTILES (JPC / 16)                   // 16 B-tiles per chunk
#define BROWS  256                          // rows per block (4 waves x 64)
#define ROWB   (DIM * 2)                    // 128 bytes per bf16 row
#define LDSB   (JPC * ROWB)                 // 32 KiB

typedef __attribute__((ext_vector_type(8))) short bf16x8;  // 8 bf16 = 4 VGPRs
typedef __attribute__((ext_vector_type(4))) float f32x4;

static __device__ __forceinline__ unsigned short f2bf(float f) {
    unsigned int u = __float_as_uint(f);
    unsigned int r = (u + 0x7fffu + ((u >> 16) & 1u)) >> 16;   // RNE
    return (unsigned short)r;
}

// ------- kernel 1: normalize rows of BOTH inputs -> bf16 (A pre-scaled) ----
__global__ __launch_bounds__(256) void nrm_bf16_kernel(
        const float* __restrict__ A, const float* __restrict__ B,
        unsigned short* __restrict__ Ab, unsigned short* __restrict__ Bb) {
    int wid  = (blockIdx.x * 256 + threadIdx.x) >> 6;   // 0..2*NROWS-1
    int lane = threadIdx.x & 63;
    const float* in;
    unsigned short* out;
    float scale;
    int row;
    if (wid < NROWS) { in = A; out = Ab; scale = SCALE; row = wid; }
    else             { in = B; out = Bb; scale = 1.0f;  row = wid - NROWS; }
    float x  = in[row * DIM + lane];
    float ss = x * x;
    #pragma unroll
    for (int m = 32; m >= 1; m >>= 1) ss += __shfl_xor(ss, m, 64);
    out[row * DIM + lane] = f2bf(x * rsqrtf(ss) * scale);
}

// -------- kernel 2: LDS-staged MFMA sim tiles + exp2 row-sum partials ------
__global__ __launch_bounds__(256) void simexp_kernel(
        const unsigned short* __restrict__ Ab,
        const unsigned short* __restrict__ Bb,
        float* __restrict__ partials) {
    __shared__ __align__(1024) unsigned char lds[LDSB];
    const int lane = threadIdx.x & 63;
    const int wid  = threadIdx.x >> 6;                  // wave in block
    const int jc   = blockIdx.x & (JC - 1);
    const int rb   = blockIdx.x / JC;
    const int i0   = rb * BROWS + wid * 64;             // wave's first A row
    const int lr   = lane & 15;                         // fragment row/col
    const int lk   = lane >> 4;                         // k-group (x8 bf16)

    // ---- stage B chunk: linear LDS dest, XOR-permuted global source ------
    // LDS(row, col16) holds global(row, col16 ^ (row&7)); each instr covers
    // 8 rows (1 KiB), so row&7 == lane>>3 inside the instr.
    const unsigned char* gB = (const unsigned char*)Bb + (size_t)jc * JPC * ROWB;
    const int perm = ((lane >> 3) << 7) | ((((lane & 7) ^ (lane >> 3))) << 4);
    #pragma unroll
    for (int i = 0; i < 8; ++i) {
        const int off = (wid * 8 + i) * 1024;           // wave's 8 slabs
        __builtin_amdgcn_global_load_lds(
            (const __attribute__((address_space(1))) void*)(gB + off + perm),
            (__attribute__((address_space(3))) void*)(&lds[off]),
            16, 0, 0);
    }

    // ---- A fragments (global/L2 loads overlap the staging latency) -------
    bf16x8 a[4][2];
    #pragma unroll
    for (int t = 0; t < 4; ++t) {
        const unsigned short* ap = Ab + (size_t)(i0 + t * 16 + lr) * DIM + lk * 8;
        a[t][0] = *(const bf16x8*)(ap);
        a[t][1] = *(const bf16x8*)(ap + 32);
    }

    float es[4][4];
    #pragma unroll
    for (int t = 0; t < 4; ++t)
        #pragma unroll
        for (int r = 0; r < 4; ++r) es[t][r] = 0.0f;

    __syncthreads();                                    // staging complete

    // ds_read bases: row lr, col16 = lk (frag0) / lk^4 (frag1), un-swizzled
    // via the same XOR; loop-invariant since row&7 == lr&7 for every tile.
    const unsigned char* lp0 = &lds[lr * ROWB + (((lk    ) ^ (lr & 7)) << 4)];
    const unsigned char* lp1 = &lds[lr * ROWB + (((lk ^ 4) ^ (lr & 7)) << 4)];

    const f32x4 zero = {0.f, 0.f, 0.f, 0.f};

    // ---- prologue: tile 0 -> accp ----
    bf16x8 c0 = *(const bf16x8*)(lp0);
    bf16x8 c1 = *(const bf16x8*)(lp1);
    f32x4 accp[4];
    #pragma unroll
    for (int t = 0; t < 4; ++t) {
        accp[t] = __builtin_amdgcn_mfma_f32_16x16x32_bf16(a[t][0], c0, zero, 0, 0, 0);
        accp[t] = __builtin_amdgcn_mfma_f32_16x16x32_bf16(a[t][1], c1, accp[t], 0, 0, 0);
    }

    // ---- steady state: ds_read(jt) | exp(jt-1) | MFMA(jt) ----
    #pragma unroll 4
    for (int jt = 1; jt < NTILES; ++jt) {
        bf16x8 n0 = *(const bf16x8*)(lp0 + jt * (16 * ROWB));
        bf16x8 n1 = *(const bf16x8*)(lp1 + jt * (16 * ROWB));
        #pragma unroll
        for (int t = 0; t < 4; ++t)
            #pragma unroll
            for (int r = 0; r < 4; ++r)
                es[t][r] += __builtin_amdgcn_exp2f(accp[t][r]);
        #pragma unroll
        for (int t = 0; t < 4; ++t) {
            accp[t] = __builtin_amdgcn_mfma_f32_16x16x32_bf16(a[t][0], n0, zero, 0, 0, 0);
            accp[t] = __builtin_amdgcn_mfma_f32_16x16x32_bf16(a[t][1], n1, accp[t], 0, 0, 0);
        }
    }
    #pragma unroll
    for (int t = 0; t < 4; ++t)
        #pragma unroll
        for (int r = 0; r < 4; ++r)
            es[t][r] += __builtin_amdgcn_exp2f(accp[t][r]);

    // es[t][r]: partial over this lane's 16-col slice of row i0+t*16+lk*4+r.
    #pragma unroll
    for (int t = 0; t < 4; ++t)
        #pragma unroll
        for (int r = 0; r < 4; ++r) {
            float v = es[t][r];
            v += __shfl_xor(v, 1, 64);
            v += __shfl_xor(v, 2, 64);
            v += __shfl_xor(v, 4, 64);
            v += __shfl_xor(v, 8, 64);
            es[t][r] = v;
        }

    if (lr == 0) {                                      // lanes 0,16,32,48
        float* pout = partials + (size_t)jc * NROWS + i0;
        #pragma unroll
        for (int t = 0; t < 4; ++t) {
            f32x4 v = {es[t][0], es[t][1], es[t][2], es[t][3]};
            *(f32x4*)(pout + t * 16 + lk * 4) = v;      // rows lk*4..lk*4+3
        }
    }
}

// -------- kernel 3: per-row loss; lane-parallel partial sum (JC==64) -------
__global__ __launch_bounds__(256) void rowloss_kernel(
        const float* __restrict__ A, const float* __restrict__ B,
        const float* __restrict__ partials, float* __restrict__ rowloss) {
    int row  = (blockIdx.x * 256 + threadIdx.x) >> 6;
    int lane = threadIdx.x & 63;
    float a = A[row * DIM + lane];
    float b = B[row * DIM + lane];
    float saa = a * a, sbb = b * b, sab = a * b;
    float S   = partials[(size_t)lane * NROWS + row];   // one chunk per lane
    #pragma unroll
    for (int m = 32; m >= 1; m >>= 1) {
        saa += __shfl_xor(saa, m, 64);
        sbb += __shfl_xor(sbb, m, 64);
        sab += __shfl_xor(sab, m, 64);
        S   += __shfl_xor(S,   m, 64);
    }
    if (lane == 0) {
        float diag = sab * rsqrtf(saa * sbb);           // exact fp32 cos-sim
        rowloss[row] = LN2 * __builtin_amdgcn_logf(S) - diag * INV_T;
    }
}

// -------- kernel 4: deterministic mean over 16384 row losses ---------------
__global__ __launch_bounds__(1024) void mean_kernel(
        const float* __restrict__ rowloss, float* __restrict__ out) {
    float s = 0.f;
    for (int idx = threadIdx.x; idx < NROWS; idx += 1024) s += rowloss[idx];
    __shared__ float red[16];
    #pragma unroll
    for (int m = 32; m >= 1; m >>= 1) s += __shfl_xor(s, m, 64);
    if ((threadIdx.x & 63) == 0) red[threadIdx.x >> 6] = s;
    __syncthreads();
    if (threadIdx.x < 16) {
        float t = red[threadIdx.x];
        #pragma unroll
        for (int m = 8; m >= 1; m >>= 1) t += __shfl_xor(t, m, 16);
        if (threadIdx.x == 0) out[0] = t * (1.0f / NROWS);
    }
}

extern "C" void kernel_launch(void* const* d_in, const int* in_sizes, int n_in,
                              void* d_out, int out_size, void* d_ws, size_t ws_size,
                              hipStream_t stream) {
    const float* A  = (const float*)d_in[0];
    const float* Bm = (const float*)d_in[1];
    float* out = (float*)d_out;

    unsigned short* Ab = (unsigned short*)d_ws;                 // 2 MiB
    unsigned short* Bb = Ab + (size_t)NROWS * DIM;              // 2 MiB
    float* partials    = (float*)(Bb + (size_t)NROWS * DIM);    // 4 MiB
    float* rowloss     = partials + (size_t)JC * NROWS;         // 64 KiB

    nrm_bf16_kernel<<<2 * NROWS / 4, 256, 0, stream>>>(A, Bm, Ab, Bb);
    simexp_kernel<<<(NROWS / BROWS) * JC, 256, 0, stream>>>(Ab, Bb, partials);
    rowloss_kernel<<<NROWS / 4, 256, 0, stream>>>(A, Bm, partials, rowloss);
    mean_kernel<<<1, 1024, 0, stream>>>(rowloss, out);
}